// Round 3
// baseline (4794.440 us; speedup 1.0000x reference)
//
#include <hip/hip_runtime.h>
#include <cstddef>

// Problem dims
#define B_  64
#define R_  49
#define F_  512
#define H_  512
#define V_  10000
#define TT  32
#define TS  31
#define NBLK 64

__device__ __forceinline__ float fsigm(float x) { return 1.0f / (1.0f + __expf(-x)); }
__device__ __forceinline__ float ftanh(float x) { return 1.0f - 2.0f / (__expf(2.0f * x) + 1.0f); }

// ---------------------------------------------------------------------------
// Generic fp32 NT GEMM (as round 1)
// ---------------------------------------------------------------------------
__global__ __launch_bounds__(256) void gemm_nt_f32(
    const float* __restrict__ A, int lda,
    const float* __restrict__ Bm, int ldb,
    const float* __restrict__ bias1, const float* __restrict__ bias2,
    float* __restrict__ C, int ldc, int M, int N, int K)
{
    __shared__ __align__(16) float As[16][68];
    __shared__ __align__(16) float Bs[16][68];
    const int tid = threadIdx.x;
    const int m0 = blockIdx.y * 64, n0 = blockIdx.x * 64;
    const int tr = tid >> 4, tc = tid & 15;
    const int lrow = tid >> 2, lk4 = (tid & 3) * 4;
    const bool am = (m0 + lrow) < M;
    const bool bn = (n0 + lrow) < N;
    const float* aptr = A + (size_t)(m0 + lrow) * lda + lk4;
    const float* bptr = Bm + (size_t)(n0 + lrow) * ldb + lk4;
    float acc[4][4] = {};

    for (int k0 = 0; k0 < K; k0 += 16) {
        float4 av = make_float4(0.f, 0.f, 0.f, 0.f);
        float4 bv = make_float4(0.f, 0.f, 0.f, 0.f);
        if (am) av = *(const float4*)(aptr + k0);
        if (bn) bv = *(const float4*)(bptr + k0);
        __syncthreads();
        As[lk4 + 0][lrow] = av.x; As[lk4 + 1][lrow] = av.y;
        As[lk4 + 2][lrow] = av.z; As[lk4 + 3][lrow] = av.w;
        Bs[lk4 + 0][lrow] = bv.x; Bs[lk4 + 1][lrow] = bv.y;
        Bs[lk4 + 2][lrow] = bv.z; Bs[lk4 + 3][lrow] = bv.w;
        __syncthreads();
#pragma unroll
        for (int kk = 0; kk < 16; ++kk) {
            float4 a = *(const float4*)&As[kk][tr * 4];
            float4 b = *(const float4*)&Bs[kk][tc * 4];
            acc[0][0] += a.x * b.x; acc[0][1] += a.x * b.y; acc[0][2] += a.x * b.z; acc[0][3] += a.x * b.w;
            acc[1][0] += a.y * b.x; acc[1][1] += a.y * b.y; acc[1][2] += a.y * b.z; acc[1][3] += a.y * b.w;
            acc[2][0] += a.z * b.x; acc[2][1] += a.z * b.y; acc[2][2] += a.z * b.z; acc[2][3] += a.z * b.w;
            acc[3][0] += a.w * b.x; acc[3][1] += a.w * b.y; acc[3][2] += a.w * b.z; acc[3][3] += a.w * b.w;
        }
    }
#pragma unroll
    for (int i = 0; i < 4; ++i) {
        int m = m0 + tr * 4 + i;
        if (m >= M) continue;
#pragma unroll
        for (int j = 0; j < 4; ++j) {
            int n = n0 + tc * 4 + j;
            if (n >= N) continue;
            float v = acc[i][j];
            if (bias1) v += bias1[n];
            if (bias2) v += bias2[n];
            C[(size_t)m * ldc + n] = v;
        }
    }
}

__global__ __launch_bounds__(256) void k_avg(const float* __restrict__ feat,
                                             float* __restrict__ avg)
{
    int id = blockIdx.x * 256 + threadIdx.x;
    int b = id >> 9, f = id & 511;
    const float* p = feat + (size_t)b * R_ * F_ + f;
    float s = 0.f;
#pragma unroll 7
    for (int r = 0; r < R_; ++r) s += p[r * F_];
    avg[id] = s * (1.0f / 49.0f);
}

// hT[j*64+b] = src[b*512+j]
__global__ __launch_bounds__(256) void k_tr(const float* __restrict__ src,
                                            float* __restrict__ dst)
{
    int id = blockIdx.x * 256 + threadIdx.x;
    int j = id >> 6, b = id & 63;
    dst[id] = src[(size_t)b * 512 + j];
}

// ---------------------------------------------------------------------------
// Persistent decode: 64 blocks x 1024 threads, all 31 steps.
// Cross-block data via agent-scope relaxed atomics (coherent, no L2 flush);
// global barrier = monotonic atomic counter (no fences -> weights stay in L2).
// Layouts: hT/ctxT/dT are [k][64 b] so lane=b loads are coalesced.
// ---------------------------------------------------------------------------
__global__ __launch_bounds__(1024) void decode_coop(
    const float* __restrict__ feat,  const float* __restrict__ encat,
    const float* __restrict__ W_dec, const float* __restrict__ b_dec,
    const float* __restrict__ v_w,   const float* __restrict__ v_b,
    const float* __restrict__ W_ih,  const float* __restrict__ W_hh,
    const float* __restrict__ embg,  const float* __restrict__ cbuf,
    float* __restrict__ hT, float* __restrict__ ctxT,
    float* __restrict__ dT, float* __restrict__ Hall,
    unsigned* __restrict__ bar)
{
    __shared__ float xls[64 * 261];   // [b][256k] pad-261 -> conflict-free
    __shared__ float smB[2048];       // phase A/C reduce | phase B scratch

    const int tid  = threadIdx.x;
    const int bid  = blockIdx.x;
    const int lane = tid & 63;
    const int w    = __builtin_amdgcn_readfirstlane(tid >> 6);   // wave id 0..15

    // persistent cell state: wave g<8 holds c[j=bid*8+g][b=lane]
    float creg = (w < 8) ? cbuf[(size_t)lane * 512 + bid * 8 + w] : 0.f;

    unsigned ibar = 0;

    auto scload = [](const float* p) {
        return __hip_atomic_load(p, __ATOMIC_RELAXED, __HIP_MEMORY_SCOPE_AGENT);
    };
    auto scstore = [](float* p, float v) {
        __hip_atomic_store(p, v, __ATOMIC_RELAXED, __HIP_MEMORY_SCOPE_AGENT);
    };

    for (int t = 0; t < TS; ++t) {
        const float* hR = hT + (size_t)(t & 1) * (H_ * 64);
        float*       hW = hT + (size_t)((t + 1) & 1) * (H_ * 64);

        // ================= phase A: dec_att (block owns 8 j) =============
        {
            float pf[16];
#pragma unroll
            for (int i = 0; i < 16; ++i)
                pf[i] = scload(hR + (size_t)(i * 16 + w) * 64 + lane);
#pragma unroll
            for (int i = 0; i < 16; ++i)
                xls[lane * 261 + i * 16 + w] = pf[i];
            __syncthreads();
#pragma unroll
            for (int i = 0; i < 16; ++i)
                pf[i] = scload(hR + (size_t)(256 + i * 16 + w) * 64 + lane);

            const int jl = w & 7, kq = w >> 3;
            const float* wd = W_dec + (size_t)(bid * 8 + jl) * 512;
            float acc = 0.f;
            const int kk0 = kq * 128;
#pragma unroll 8
            for (int kk = kk0; kk < kk0 + 128; ++kk)
                acc += wd[kk] * xls[lane * 261 + kk];
            __syncthreads();
#pragma unroll
            for (int i = 0; i < 16; ++i)
                xls[lane * 261 + i * 16 + w] = pf[i];
            __syncthreads();
#pragma unroll 8
            for (int kk = kk0; kk < kk0 + 128; ++kk)
                acc += wd[256 + kk] * xls[lane * 261 + kk];

            smB[w * 64 + lane] = acc;
            __syncthreads();
            if (w < 8) {
                float da = smB[w * 64 + lane] + smB[(w + 8) * 64 + lane]
                         + b_dec[bid * 8 + w];
                scstore(dT + (size_t)(bid * 8 + w) * 64 + lane, da);
            }
        }
        // -------- global barrier 1 --------
        ++ibar; __syncthreads();
        if (tid == 0) {
            __hip_atomic_fetch_add(bar, 1u, __ATOMIC_RELAXED, __HIP_MEMORY_SCOPE_AGENT);
            while (__hip_atomic_load(bar, __ATOMIC_RELAXED, __HIP_MEMORY_SCOPE_AGENT)
                   < (unsigned)NBLK * ibar) {}
        }
        __syncthreads();

        // ================= phase B: e/softmax/ctx (block = b) ============
        {
            const int b = bid;
            if (tid < 512) smB[tid] = scload(dT + (size_t)tid * 64 + b);
            __syncthreads();
            for (int r = w; r < R_; r += 16) {
                const float* er = encat + ((size_t)b * R_ + r) * 512;
                float s = 0.f;
#pragma unroll
                for (int i = 0; i < 8; ++i) {
                    int j = i * 64 + lane;
                    s += ftanh(er[j] + smB[j]) * v_w[j];
                }
#pragma unroll
                for (int off = 32; off; off >>= 1) s += __shfl_down(s, off, 64);
                if (lane == 0) smB[1536 + r] = s + v_b[0];
            }
            __syncthreads();
            if (tid < 64) {
                float x = (lane < R_) ? smB[1536 + lane] : -1e30f;
                float mx = x;
#pragma unroll
                for (int off = 32; off; off >>= 1) mx = fmaxf(mx, __shfl_xor(mx, off, 64));
                float ex = (lane < R_) ? __expf(x - mx) : 0.f;
                float sm = ex;
#pragma unroll
                for (int off = 32; off; off >>= 1) sm += __shfl_xor(sm, off, 64);
                if (lane < R_) smB[1600 + lane] = ex / sm;
            }
            __syncthreads();
            {
                int f = tid & 511, rh = tid >> 9;
                const float* fp = feat + (size_t)b * R_ * F_ + f;
                float s = 0.f;
                int rs = rh * 25, re = rh ? R_ : 25;
                for (int r = rs; r < re; ++r) s += smB[1600 + r] * fp[(size_t)r * 512];
                smB[512 + rh * 512 + f] = s;
            }
            __syncthreads();
            if (tid < 512)
                scstore(ctxT + (size_t)tid * 64 + bid, smB[512 + tid] + smB[1024 + tid]);
        }
        // -------- global barrier 2 --------
        ++ibar; __syncthreads();
        if (tid == 0) {
            __hip_atomic_fetch_add(bar, 1u, __ATOMIC_RELAXED, __HIP_MEMORY_SCOPE_AGENT);
            while (__hip_atomic_load(bar, __ATOMIC_RELAXED, __HIP_MEMORY_SCOPE_AGENT)
                   < (unsigned)NBLK * ibar) {}
        }
        __syncthreads();

        // ================= phase C: gates + LSTM (block owns 8 j) ========
        {
            float pf[16];
            float acc0 = 0.f, acc1 = 0.f;
            const int r0 = 2 * w, r1 = 2 * w + 1;         // rows = j_l*4+gate
            const int grow0 = (r0 & 3) * 512 + bid * 8 + (r0 >> 2);
            const int grow1 = (r1 & 3) * 512 + bid * 8 + (r1 >> 2);

#pragma unroll
            for (int i = 0; i < 16; ++i)
                pf[i] = scload(ctxT + (size_t)(i * 16 + w) * 64 + lane);

            for (int cc = 0; cc < 4; ++cc) {
#pragma unroll
                for (int i = 0; i < 16; ++i)
                    xls[lane * 261 + i * 16 + w] = pf[i];
                __syncthreads();
                if (cc < 3) {
                    int kb = (cc + 1) * 256;
#pragma unroll
                    for (int i = 0; i < 16; ++i) {
                        int k = kb + i * 16 + w;
                        const float* src = (k < 512)
                            ? (ctxT + (size_t)k * 64 + lane)
                            : (hR + (size_t)(k - 512) * 64 + lane);
                        pf[i] = scload(src);
                    }
                }
                const float* wp0 = (cc < 2)
                    ? (W_ih + (size_t)grow0 * 1024 + 512 + cc * 256)
                    : (W_hh + (size_t)grow0 * 512 + (cc - 2) * 256);
                const float* wp1 = (cc < 2)
                    ? (W_ih + (size_t)grow1 * 1024 + 512 + cc * 256)
                    : (W_hh + (size_t)grow1 * 512 + (cc - 2) * 256);
                const float* xp = &xls[lane * 261];
#pragma unroll 8
                for (int kk = 0; kk < 256; ++kk) {
                    float x = xp[kk];
                    acc0 += wp0[kk] * x;
                    acc1 += wp1[kk] * x;
                }
                __syncthreads();
            }
            smB[r0 * 64 + lane] = acc0;
            smB[r1 * 64 + lane] = acc1;
            __syncthreads();
            if (w < 8) {
                const int j = bid * 8 + w;
                float gv[4];
#pragma unroll
                for (int g = 0; g < 4; ++g)
                    gv[g] = smB[(w * 4 + g) * 64 + lane]
                          + embg[((size_t)lane * TT + t) * 2048 + g * 512 + j];
                float ig = fsigm(gv[0]), fg = fsigm(gv[1]);
                float gg = ftanh(gv[2]), og = fsigm(gv[3]);
                creg = fg * creg + ig * gg;
                float hn = og * ftanh(creg);
                scstore(hW + (size_t)j * 64 + lane, hn);
                Hall[((size_t)lane * TS + t) * 512 + j] = hn;
            }
        }
        // -------- global barrier 3 --------
        ++ibar; __syncthreads();
        if (tid == 0) {
            __hip_atomic_fetch_add(bar, 1u, __ATOMIC_RELAXED, __HIP_MEMORY_SCOPE_AGENT);
            while (__hip_atomic_load(bar, __ATOMIC_RELAXED, __HIP_MEMORY_SCOPE_AGENT)
                   < (unsigned)NBLK * ibar) {}
        }
        __syncthreads();
    }
}

// ---------------------------------------------------------------------------
extern "C" void kernel_launch(void* const* d_in, const int* in_sizes, int n_in,
                              void* d_out, int out_size, void* d_ws, size_t ws_size,
                              hipStream_t stream)
{
    (void)in_sizes; (void)n_in; (void)out_size; (void)ws_size;
    const float* feat     = (const float*)d_in[0];
    const float* caps     = (const float*)d_in[1];
    const float* W_enc    = (const float*)d_in[2];
    const float* b_enc    = (const float*)d_in[3];
    const float* W_dec    = (const float*)d_in[4];
    const float* b_dec    = (const float*)d_in[5];
    const float* v_w      = (const float*)d_in[6];
    const float* v_b      = (const float*)d_in[7];
    const float* W_ih     = (const float*)d_in[8];
    const float* W_hh     = (const float*)d_in[9];
    const float* b_ih     = (const float*)d_in[10];
    const float* b_hh     = (const float*)d_in[11];
    const float* W_init_h = (const float*)d_in[12];
    const float* b_init_h = (const float*)d_in[13];
    const float* W_init_c = (const float*)d_in[14];
    const float* b_init_c = (const float*)d_in[15];
    const float* W_out    = (const float*)d_in[16];
    const float* b_out    = (const float*)d_in[17];
    float* out = (float*)d_out;
    float* ws  = (float*)d_ws;

    // workspace (floats), ~27.9 MB; avg aliases dT, h0tmp aliases ctxT
    float* dT    = ws;                       // 32768   (pre-phase: avg)
    float* ctxT  = ws + 32768;               // 32768   (pre-phase: h0tmp)
    float* cbuf  = ws + 65536;               // 32768
    float* hT    = ws + 98304;               // 65536 (ping-pong [j][b])
    float* encat = ws + 163840;              // 1605632
    float* embg  = encat + (size_t)B_ * R_ * H_;    // 4194304
    float* Hall  = embg + (size_t)B_ * TT * 2048;   // 1015808
    unsigned* bar = (unsigned*)(Hall + (size_t)B_ * TS * H_);

    float* avg   = dT;     // alias (dead before decode writes dT)
    float* h0tmp = ctxT;   // alias (dead before decode writes ctxT)

    hipMemsetAsync(bar, 0, 4, stream);

    dim3 thr(256);
    k_avg<<<128, thr, 0, stream>>>(feat, avg);
    gemm_nt_f32<<<dim3(8, 1), thr, 0, stream>>>(avg, 512, W_init_h, 512, b_init_h, nullptr,
                                                h0tmp, 512, 64, 512, 512);
    gemm_nt_f32<<<dim3(8, 1), thr, 0, stream>>>(avg, 512, W_init_c, 512, b_init_c, nullptr,
                                                cbuf, 512, 64, 512, 512);
    gemm_nt_f32<<<dim3(8, 49), thr, 0, stream>>>(feat, 512, W_enc, 512, b_enc, nullptr,
                                                 encat, 512, 3136, 512, 512);
    gemm_nt_f32<<<dim3(32, 32), thr, 0, stream>>>(caps, 512, W_ih, 1024, b_ih, b_hh,
                                                  embg, 2048, 2048, 2048, 512);
    k_tr<<<128, thr, 0, stream>>>(h0tmp, hT);   // hT0[j][b]

    {
        const float* a0 = feat;  const float* a1 = encat;
        const float* a2 = W_dec; const float* a3 = b_dec;
        const float* a4 = v_w;   const float* a5 = v_b;
        const float* a6 = W_ih;  const float* a7 = W_hh;
        const float* a8 = embg;  const float* a9 = cbuf;
        float* a10 = hT; float* a11 = ctxT; float* a12 = dT; float* a13 = Hall;
        unsigned* a14 = bar;
        void* args[] = { &a0, &a1, &a2, &a3, &a4, &a5, &a6, &a7,
                         &a8, &a9, &a10, &a11, &a12, &a13, &a14 };
        hipLaunchCooperativeKernel((const void*)decode_coop, dim3(NBLK), dim3(1024),
                                   args, 0, stream);
    }

    gemm_nt_f32<<<dim3(157, 31), thr, 0, stream>>>(Hall, 512, W_out, 512, b_out, nullptr,
                                                   out, 10000, 1984, 10000, 512);
}

// Round 4
// 3925.187 us; speedup vs baseline: 1.2215x; 1.2215x over previous
//
#include <hip/hip_runtime.h>
#include <cstddef>

// Problem dims
#define B_  64
#define R_  49
#define F_  512
#define H_  512
#define V_  10000
#define TT  32
#define TS  31
#define NBLK 64

__device__ __forceinline__ float fsigm(float x) { return 1.0f / (1.0f + __expf(-x)); }
__device__ __forceinline__ float ftanh(float x) { return 1.0f - 2.0f / (__expf(2.0f * x) + 1.0f); }

// Coherent (L2-bypassing) loads/stores, batched manually. sc0 sc1 = device scope.
__device__ __forceinline__ float4 sc_load4(const float* p) {
    float4 v;
    asm volatile("global_load_dwordx4 %0, %1, off sc0 sc1" : "=v"(v) : "v"(p));
    return v;
}
__device__ __forceinline__ float sc_load1(const float* p) {
    float v;
    asm volatile("global_load_dword %0, %1, off sc0 sc1" : "=v"(v) : "v"(p));
    return v;
}
__device__ __forceinline__ void sc_store1(float* p, float v) {
    asm volatile("global_store_dword %0, %1, off sc0 sc1" :: "v"(p), "v"(v) : "memory");
}
__device__ __forceinline__ void vm_wait0() {
    asm volatile("s_waitcnt vmcnt(0)" ::: "memory");
    __builtin_amdgcn_sched_barrier(0);
}

// ---------------------------------------------------------------------------
// Generic fp32 NT GEMM (as round 1)
// ---------------------------------------------------------------------------
__global__ __launch_bounds__(256) void gemm_nt_f32(
    const float* __restrict__ A, int lda,
    const float* __restrict__ Bm, int ldb,
    const float* __restrict__ bias1, const float* __restrict__ bias2,
    float* __restrict__ C, int ldc, int M, int N, int K)
{
    __shared__ __align__(16) float As[16][68];
    __shared__ __align__(16) float Bs[16][68];
    const int tid = threadIdx.x;
    const int m0 = blockIdx.y * 64, n0 = blockIdx.x * 64;
    const int tr = tid >> 4, tc = tid & 15;
    const int lrow = tid >> 2, lk4 = (tid & 3) * 4;
    const bool am = (m0 + lrow) < M;
    const bool bn = (n0 + lrow) < N;
    const float* aptr = A + (size_t)(m0 + lrow) * lda + lk4;
    const float* bptr = Bm + (size_t)(n0 + lrow) * ldb + lk4;
    float acc[4][4] = {};

    for (int k0 = 0; k0 < K; k0 += 16) {
        float4 av = make_float4(0.f, 0.f, 0.f, 0.f);
        float4 bv = make_float4(0.f, 0.f, 0.f, 0.f);
        if (am) av = *(const float4*)(aptr + k0);
        if (bn) bv = *(const float4*)(bptr + k0);
        __syncthreads();
        As[lk4 + 0][lrow] = av.x; As[lk4 + 1][lrow] = av.y;
        As[lk4 + 2][lrow] = av.z; As[lk4 + 3][lrow] = av.w;
        Bs[lk4 + 0][lrow] = bv.x; Bs[lk4 + 1][lrow] = bv.y;
        Bs[lk4 + 2][lrow] = bv.z; Bs[lk4 + 3][lrow] = bv.w;
        __syncthreads();
#pragma unroll
        for (int kk = 0; kk < 16; ++kk) {
            float4 a = *(const float4*)&As[kk][tr * 4];
            float4 b = *(const float4*)&Bs[kk][tc * 4];
            acc[0][0] += a.x * b.x; acc[0][1] += a.x * b.y; acc[0][2] += a.x * b.z; acc[0][3] += a.x * b.w;
            acc[1][0] += a.y * b.x; acc[1][1] += a.y * b.y; acc[1][2] += a.y * b.z; acc[1][3] += a.y * b.w;
            acc[2][0] += a.z * b.x; acc[2][1] += a.z * b.y; acc[2][2] += a.z * b.z; acc[2][3] += a.z * b.w;
            acc[3][0] += a.w * b.x; acc[3][1] += a.w * b.y; acc[3][2] += a.w * b.z; acc[3][3] += a.w * b.w;
        }
    }
#pragma unroll
    for (int i = 0; i < 4; ++i) {
        int m = m0 + tr * 4 + i;
        if (m >= M) continue;
#pragma unroll
        for (int j = 0; j < 4; ++j) {
            int n = n0 + tc * 4 + j;
            if (n >= N) continue;
            float v = acc[i][j];
            if (bias1) v += bias1[n];
            if (bias2) v += bias2[n];
            C[(size_t)m * ldc + n] = v;
        }
    }
}

__global__ __launch_bounds__(256) void k_avg(const float* __restrict__ feat,
                                             float* __restrict__ avg)
{
    int id = blockIdx.x * 256 + threadIdx.x;
    int b = id >> 9, f = id & 511;
    const float* p = feat + (size_t)b * R_ * F_ + f;
    float s = 0.f;
#pragma unroll 7
    for (int r = 0; r < R_; ++r) s += p[r * F_];
    avg[id] = s * (1.0f / 49.0f);
}

// hT[j*64+b] = src[b*512+j]
__global__ __launch_bounds__(256) void k_tr(const float* __restrict__ src,
                                            float* __restrict__ dst)
{
    int id = blockIdx.x * 256 + threadIdx.x;
    int j = id >> 6, b = id & 63;
    dst[id] = src[(size_t)b * 512 + j];
}

// Hall[(b*31+t)*512 + j] = HallT[(t*512+j)*64 + b]
__global__ __launch_bounds__(256) void k_trH(const float* __restrict__ HallT,
                                             float* __restrict__ Hall)
{
    int id = blockIdx.x * 256 + threadIdx.x;     // 0 .. 1984*512-1
    int j = id & 511, m = id >> 9;
    int b = m / 31, t = m - b * 31;
    Hall[id] = HallT[((size_t)t * 512 + j) * 64 + b];
}

// ---------------------------------------------------------------------------
// Persistent decode, v3: 64 blocks x 1024 threads.
// LDS x-tile [512 k][64 b] (conflict-free both sides, no transpose).
// Wave w: m = w&7, khalf = w>>3. Owns 4 gate rows (g=0..3, j=bid*8+m) and the
// dec row j over its k-half. Weight loads uniform (s_load) float4; x from LDS.
// Cross-block exchange: asm sc0sc1 loads/stores, batched, barrier-separated.
// ---------------------------------------------------------------------------
__global__ __launch_bounds__(1024, 1) void decode_coop(
    const float* __restrict__ feat,  const float* __restrict__ encat,
    const float* __restrict__ W_dec, const float* __restrict__ b_dec,
    const float* __restrict__ v_w,   const float* __restrict__ v_b,
    const float* __restrict__ W_ih,  const float* __restrict__ W_hh,
    const float* __restrict__ embg,  const float* __restrict__ cbuf,
    float* __restrict__ hT, float* __restrict__ ctxT,
    float* __restrict__ dTb, float* __restrict__ HallT,
    unsigned* __restrict__ bar)
{
    __shared__ float xls[512 * 64];   // x[k][b], 128 KB
    __shared__ float red[4096];       // reduce / P2 scratch, 16 KB

    const int tid  = threadIdx.x;
    const int bid  = blockIdx.x;
    const int lane = tid & 63;
    const int w    = __builtin_amdgcn_readfirstlane(tid >> 6);  // 0..15
    const int m    = w & 7, kh = w >> 3;

    // persistent cell state: thread tid<512 owns c[j=bid*8+(tid>>6)][b=tid&63]
    float creg = 0.f;
    if (tid < 512) creg = cbuf[(size_t)(tid & 63) * 512 + bid * 8 + (tid >> 6)];

    unsigned ibar = 0;

    auto gbar = [&]() {
        vm_wait0();
        __syncthreads();
        ++ibar;
        if (tid == 0) {
            __hip_atomic_fetch_add(bar, 1u, __ATOMIC_RELAXED, __HIP_MEMORY_SCOPE_AGENT);
            while (__hip_atomic_load(bar, __ATOMIC_RELAXED, __HIP_MEMORY_SCOPE_AGENT)
                   < (unsigned)NBLK * ibar)
                __builtin_amdgcn_s_sleep(2);
        }
        __syncthreads();
    };

    // stage a [512][64] fp32 array into xls via batched coherent dwordx4
    const int kb_ing = ((tid >> 6) << 2) + ((tid & 63) >> 4);   // 0..63
    const int f4_ing = (tid & 15) << 2;                          // 0..60
    auto ingest = [&](const float* src) {
        float4 pf[8];
#pragma unroll
        for (int i = 0; i < 8; ++i)
            pf[i] = sc_load4(src + (size_t)(i * 64 + kb_ing) * 64 + f4_ing);
        vm_wait0();
#pragma unroll
        for (int i = 0; i < 8; ++i)
            *(float4*)&xls[(i * 64 + kb_ing) * 64 + f4_ing] = pf[i];
    };

    for (int t = 0; t < TS; ++t) {
        const float* hR = hT + (size_t)(t & 1) * (H_ * 64);
        float*       hW = hT + (size_t)((t + 1) & 1) * (H_ * 64);

        // gate accumulators (live P1 -> P3)
        float ga0 = 0.f, ga1 = 0.f, ga2 = 0.f, ga3 = 0.f;

        // ============ P1: h ingest; dec_att + W_hh*h partials ============
        ingest(hR);
        __syncthreads();
        {
            const int j = bid * 8 + m;
            const float* w0p = W_hh + (size_t)(0 * 512 + j) * 512 + kh * 256;
            const float* w1p = W_hh + (size_t)(1 * 512 + j) * 512 + kh * 256;
            const float* w2p = W_hh + (size_t)(2 * 512 + j) * 512 + kh * 256;
            const float* w3p = W_hh + (size_t)(3 * 512 + j) * 512 + kh * 256;
            const float* wdp = W_dec + (size_t)j * 512 + kh * 256;
            const float* xk  = &xls[kh * 256 * 64 + lane];
            float ad = 0.f;
#pragma unroll 4
            for (int kk = 0; kk < 256; kk += 4) {
                float x0 = xk[(kk + 0) * 64], x1 = xk[(kk + 1) * 64];
                float x2 = xk[(kk + 2) * 64], x3 = xk[(kk + 3) * 64];
                float4 q0 = *(const float4*)(w0p + kk);
                float4 q1 = *(const float4*)(w1p + kk);
                float4 q2 = *(const float4*)(w2p + kk);
                float4 q3 = *(const float4*)(w3p + kk);
                float4 qd = *(const float4*)(wdp + kk);
                ga0 += q0.x * x0 + q0.y * x1 + q0.z * x2 + q0.w * x3;
                ga1 += q1.x * x0 + q1.y * x1 + q1.z * x2 + q1.w * x3;
                ga2 += q2.x * x0 + q2.y * x1 + q2.z * x2 + q2.w * x3;
                ga3 += q3.x * x0 + q3.y * x1 + q3.z * x2 + q3.w * x3;
                ad  += qd.x * x0 + qd.y * x1 + qd.z * x2 + qd.w * x3;
            }
            red[(kh * 8 + m) * 64 + lane] = ad;
        }
        __syncthreads();
        if (tid < 512) {
            int jl = tid >> 6, b = tid & 63;
            float da = red[jl * 64 + b] + red[(8 + jl) * 64 + b] + b_dec[bid * 8 + jl];
            sc_store1(&dTb[(size_t)b * 512 + bid * 8 + jl], da);
        }
        gbar();

        // ============ P2: e / softmax / ctx for b = bid ===================
        {
            const int b = bid;
            if (tid < 128) {
                float4 dv = sc_load4(dTb + (size_t)b * 512 + tid * 4);
                vm_wait0();
                *(float4*)&red[tid << 2] = dv;     // da in red[0..511]
            }
            __syncthreads();
            for (int r = w; r < R_; r += 16) {
                const float* er = encat + ((size_t)b * R_ + r) * 512;
                float s = 0.f;
#pragma unroll
                for (int i = 0; i < 8; ++i) {
                    int jj = i * 64 + lane;
                    s += ftanh(er[jj] + red[jj]) * v_w[jj];
                }
#pragma unroll
                for (int off = 32; off; off >>= 1) s += __shfl_down(s, off, 64);
                if (lane == 0) red[1088 + r] = s + v_b[0];
            }
            __syncthreads();
            if (tid < 64) {
                float x = (lane < R_) ? red[1088 + lane] : -1e30f;
                float mx = x;
#pragma unroll
                for (int off = 32; off; off >>= 1) mx = fmaxf(mx, __shfl_xor(mx, off, 64));
                float ex = (lane < R_) ? __expf(x - mx) : 0.f;
                float sm = ex;
#pragma unroll
                for (int off = 32; off; off >>= 1) sm += __shfl_xor(sm, off, 64);
                if (lane < R_) red[1152 + lane] = ex / sm;
            }
            __syncthreads();
            {
                int f = tid & 511, rh = tid >> 9;
                const float* fp = feat + (size_t)b * R_ * F_ + f;
                float s = 0.f;
                int rs = rh * 25, re = rh ? R_ : 25;
                for (int r = rs; r < re; ++r) s += red[1152 + r] * fp[(size_t)r * 512];
                __syncthreads();                       // da fully consumed
                red[rh * 512 + f] = s;
            }
            __syncthreads();
            if (tid < 512)
                sc_store1(&ctxT[(size_t)tid * 64 + bid], red[tid] + red[512 + tid]);
        }
        gbar();

        // ============ P3: ctx ingest; gates += W_ihc*ctx; LSTM ============
        ingest(ctxT);
        __syncthreads();
        {
            const int j = bid * 8 + m;
            const float* w0p = W_ih + (size_t)(0 * 512 + j) * 1024 + 512 + kh * 256;
            const float* w1p = W_ih + (size_t)(1 * 512 + j) * 1024 + 512 + kh * 256;
            const float* w2p = W_ih + (size_t)(2 * 512 + j) * 1024 + 512 + kh * 256;
            const float* w3p = W_ih + (size_t)(3 * 512 + j) * 1024 + 512 + kh * 256;
            const float* xk  = &xls[kh * 256 * 64 + lane];
#pragma unroll 4
            for (int kk = 0; kk < 256; kk += 4) {
                float x0 = xk[(kk + 0) * 64], x1 = xk[(kk + 1) * 64];
                float x2 = xk[(kk + 2) * 64], x3 = xk[(kk + 3) * 64];
                float4 q0 = *(const float4*)(w0p + kk);
                float4 q1 = *(const float4*)(w1p + kk);
                float4 q2 = *(const float4*)(w2p + kk);
                float4 q3 = *(const float4*)(w3p + kk);
                ga0 += q0.x * x0 + q0.y * x1 + q0.z * x2 + q0.w * x3;
                ga1 += q1.x * x0 + q1.y * x1 + q1.z * x2 + q1.w * x3;
                ga2 += q2.x * x0 + q2.y * x1 + q2.z * x2 + q2.w * x3;
                ga3 += q3.x * x0 + q3.y * x1 + q3.z * x2 + q3.w * x3;
            }
            red[kh * 2048 + (m * 4 + 0) * 64 + lane] = ga0;
            red[kh * 2048 + (m * 4 + 1) * 64 + lane] = ga1;
            red[kh * 2048 + (m * 4 + 2) * 64 + lane] = ga2;
            red[kh * 2048 + (m * 4 + 3) * 64 + lane] = ga3;
        }
        __syncthreads();
        if (tid < 512) {
            int jl = tid >> 6, b = tid & 63;
            int j = bid * 8 + jl;
            float gv[4];
#pragma unroll
            for (int g = 0; g < 4; ++g)
                gv[g] = red[(jl * 4 + g) * 64 + b] + red[2048 + (jl * 4 + g) * 64 + b]
                      + embg[((size_t)b * TT + t) * 2048 + g * 512 + j];
            float ig = fsigm(gv[0]), fg = fsigm(gv[1]);
            float gg = ftanh(gv[2]), og = fsigm(gv[3]);
            creg = fg * creg + ig * gg;
            float hn = og * ftanh(creg);
            sc_store1(&hW[(size_t)j * 64 + b], hn);
            HallT[((size_t)t * 512 + j) * 64 + b] = hn;   // normal store
        }
        gbar();
    }
}

// ---------------------------------------------------------------------------
extern "C" void kernel_launch(void* const* d_in, const int* in_sizes, int n_in,
                              void* d_out, int out_size, void* d_ws, size_t ws_size,
                              hipStream_t stream)
{
    (void)in_sizes; (void)n_in; (void)out_size; (void)ws_size;
    const float* feat     = (const float*)d_in[0];
    const float* caps     = (const float*)d_in[1];
    const float* W_enc    = (const float*)d_in[2];
    const float* b_enc    = (const float*)d_in[3];
    const float* W_dec    = (const float*)d_in[4];
    const float* b_dec    = (const float*)d_in[5];
    const float* v_w      = (const float*)d_in[6];
    const float* v_b      = (const float*)d_in[7];
    const float* W_ih     = (const float*)d_in[8];
    const float* W_hh     = (const float*)d_in[9];
    const float* b_ih     = (const float*)d_in[10];
    const float* b_hh     = (const float*)d_in[11];
    const float* W_init_h = (const float*)d_in[12];
    const float* b_init_h = (const float*)d_in[13];
    const float* W_init_c = (const float*)d_in[14];
    const float* b_init_c = (const float*)d_in[15];
    const float* W_out    = (const float*)d_in[16];
    const float* b_out    = (const float*)d_in[17];
    float* out = (float*)d_out;
    float* ws  = (float*)d_ws;

    // workspace (floats), ~27.9 MB
    float* dTb   = ws;                                   // 32768  (pre: avg)
    float* ctxT  = ws + 32768;                           // 32768  (pre: h0tmp)
    float* cbuf  = ws + 65536;                           // 32768
    float* hT    = ws + 98304;                           // 65536 ping-pong [j][b]
    float* encat = ws + 163840;                          // 1,605,632
    float* embg  = encat + (size_t)B_ * R_ * H_;         // 4,194,304
    float* HallT = embg + (size_t)B_ * TT * 2048;        // 1,015,808
    unsigned* bar = (unsigned*)(HallT + (size_t)TS * H_ * B_);

    float* avg   = dTb;    // alias (dead before decode writes dTb)
    float* h0tmp = ctxT;   // alias (dead before decode writes ctxT)
    float* Hall  = embg;   // alias (embg dead after decode)

    hipMemsetAsync(bar, 0, 4, stream);

    dim3 thr(256);
    k_avg<<<128, thr, 0, stream>>>(feat, avg);
    gemm_nt_f32<<<dim3(8, 1), thr, 0, stream>>>(avg, 512, W_init_h, 512, b_init_h, nullptr,
                                                h0tmp, 512, 64, 512, 512);
    gemm_nt_f32<<<dim3(8, 1), thr, 0, stream>>>(avg, 512, W_init_c, 512, b_init_c, nullptr,
                                                cbuf, 512, 64, 512, 512);
    gemm_nt_f32<<<dim3(8, 49), thr, 0, stream>>>(feat, 512, W_enc, 512, b_enc, nullptr,
                                                 encat, 512, 3136, 512, 512);
    gemm_nt_f32<<<dim3(32, 32), thr, 0, stream>>>(caps, 512, W_ih, 1024, b_ih, b_hh,
                                                  embg, 2048, 2048, 2048, 512);
    k_tr<<<128, thr, 0, stream>>>(h0tmp, hT);   // hT0[j][b]

    {
        const float* a0 = feat;  const float* a1 = encat;
        const float* a2 = W_dec; const float* a3 = b_dec;
        const float* a4 = v_w;   const float* a5 = v_b;
        const float* a6 = W_ih;  const float* a7 = W_hh;
        const float* a8 = embg;  const float* a9 = cbuf;
        float* a10 = hT; float* a11 = ctxT; float* a12 = dTb; float* a13 = HallT;
        unsigned* a14 = bar;
        void* args[] = { &a0, &a1, &a2, &a3, &a4, &a5, &a6, &a7,
                         &a8, &a9, &a10, &a11, &a12, &a13, &a14 };
        hipLaunchCooperativeKernel((const void*)decode_coop, dim3(NBLK), dim3(1024),
                                   args, 0, stream);
    }

    // HallT[t][j][b] -> Hall[(b*31+t)][j]   (Hall aliases dead embg)
    k_trH<<<3968, thr, 0, stream>>>(HallT, Hall);

    // logits = Hall @ W_out.T + b_out
    gemm_nt_f32<<<dim3(157, 31), thr, 0, stream>>>(Hall, 512, W_out, 512, b_out, nullptr,
                                                   out, 10000, 1984, 10000, 512);
}

// Round 5
// 1693.350 us; speedup vs baseline: 2.8313x; 2.3180x over previous
//
#include <hip/hip_runtime.h>
#include <cstddef>

// Problem dims
#define B_  64
#define R_  49
#define F_  512
#define H_  512
#define V_  10000
#define TT  32
#define TS  31

__device__ __forceinline__ float fsigm(float x) { return 1.0f / (1.0f + __expf(-x)); }
__device__ __forceinline__ float ftanh(float x) { return 1.0f - 2.0f / (__expf(2.0f * x) + 1.0f); }

// ---------------------------------------------------------------------------
// Generic fp32 NT GEMM (as round 1)
// ---------------------------------------------------------------------------
__global__ __launch_bounds__(256) void gemm_nt_f32(
    const float* __restrict__ A, int lda,
    const float* __restrict__ Bm, int ldb,
    const float* __restrict__ bias1, const float* __restrict__ bias2,
    float* __restrict__ C, int ldc, int M, int N, int K)
{
    __shared__ __align__(16) float As[16][68];
    __shared__ __align__(16) float Bs[16][68];
    const int tid = threadIdx.x;
    const int m0 = blockIdx.y * 64, n0 = blockIdx.x * 64;
    const int tr = tid >> 4, tc = tid & 15;
    const int lrow = tid >> 2, lk4 = (tid & 3) * 4;
    const bool am = (m0 + lrow) < M;
    const bool bn = (n0 + lrow) < N;
    const float* aptr = A + (size_t)(m0 + lrow) * lda + lk4;
    const float* bptr = Bm + (size_t)(n0 + lrow) * ldb + lk4;
    float acc[4][4] = {};

    for (int k0 = 0; k0 < K; k0 += 16) {
        float4 av = make_float4(0.f, 0.f, 0.f, 0.f);
        float4 bv = make_float4(0.f, 0.f, 0.f, 0.f);
        if (am) av = *(const float4*)(aptr + k0);
        if (bn) bv = *(const float4*)(bptr + k0);
        __syncthreads();
        As[lk4 + 0][lrow] = av.x; As[lk4 + 1][lrow] = av.y;
        As[lk4 + 2][lrow] = av.z; As[lk4 + 3][lrow] = av.w;
        Bs[lk4 + 0][lrow] = bv.x; Bs[lk4 + 1][lrow] = bv.y;
        Bs[lk4 + 2][lrow] = bv.z; Bs[lk4 + 3][lrow] = bv.w;
        __syncthreads();
#pragma unroll
        for (int kk = 0; kk < 16; ++kk) {
            float4 a = *(const float4*)&As[kk][tr * 4];
            float4 b = *(const float4*)&Bs[kk][tc * 4];
            acc[0][0] += a.x * b.x; acc[0][1] += a.x * b.y; acc[0][2] += a.x * b.z; acc[0][3] += a.x * b.w;
            acc[1][0] += a.y * b.x; acc[1][1] += a.y * b.y; acc[1][2] += a.y * b.z; acc[1][3] += a.y * b.w;
            acc[2][0] += a.z * b.x; acc[2][1] += a.z * b.y; acc[2][2] += a.z * b.z; acc[2][3] += a.z * b.w;
            acc[3][0] += a.w * b.x; acc[3][1] += a.w * b.y; acc[3][2] += a.w * b.z; acc[3][3] += a.w * b.w;
        }
    }
#pragma unroll
    for (int i = 0; i < 4; ++i) {
        int m = m0 + tr * 4 + i;
        if (m >= M) continue;
#pragma unroll
        for (int j = 0; j < 4; ++j) {
            int n = n0 + tc * 4 + j;
            if (n >= N) continue;
            float v = acc[i][j];
            if (bias1) v += bias1[n];
            if (bias2) v += bias2[n];
            C[(size_t)m * ldc + n] = v;
        }
    }
}

__global__ __launch_bounds__(256) void k_avg(const float* __restrict__ feat,
                                             float* __restrict__ avg)
{
    int id = blockIdx.x * 256 + threadIdx.x;
    int b = id >> 9, f = id & 511;
    const float* p = feat + (size_t)b * R_ * F_ + f;
    float s = 0.f;
#pragma unroll 7
    for (int r = 0; r < R_; ++r) s += p[r * F_];
    avg[id] = s * (1.0f / 49.0f);
}

// dst[j*64+b] = src[b*512+j]
__global__ __launch_bounds__(256) void k_tr(const float* __restrict__ src,
                                            float* __restrict__ dst)
{
    int id = blockIdx.x * 256 + threadIdx.x;
    int j = id >> 6, b = id & 63;
    dst[id] = src[(size_t)b * 512 + j];
}

// Hall[(b*31+t)*512 + j] = HallT[(t*512+j)*64 + b]
__global__ __launch_bounds__(256) void k_trH(const float* __restrict__ HallT,
                                             float* __restrict__ Hall)
{
    int id = blockIdx.x * 256 + threadIdx.x;     // 0 .. 1984*512-1
    int j = id & 511, m = id >> 9;
    int b = m / 31, t = m - b * 31;
    Hall[id] = HallT[((size_t)t * 512 + j) * 64 + b];
}

// ---------------------------------------------------------------------------
// K1: dec_att. Block owns rows {2bid, 2bid+1} of W_dec. lane=b, wave=k-quarter.
// ---------------------------------------------------------------------------
__global__ __launch_bounds__(256) void kStep1(
    const float* __restrict__ hT, const float* __restrict__ W_dec,
    const float* __restrict__ b_dec, float* __restrict__ dTT)
{
    __shared__ float red[8][64];
    const int tid = threadIdx.x, bid = blockIdx.x;
    const int lane = tid & 63, w = tid >> 6;
    const int j0 = 2 * bid;
    const float* w0 = W_dec + (size_t)j0 * 512;
    const float* w1 = w0 + 512;
    float a0 = 0.f, a1 = 0.f;
#pragma unroll 8
    for (int j = 128 * w; j < 128 * w + 128; ++j) {
        float x = hT[j * 64 + lane];
        a0 += w0[j] * x;
        a1 += w1[j] * x;
    }
    red[w * 2 + 0][lane] = a0;
    red[w * 2 + 1][lane] = a1;
    __syncthreads();
    if (tid < 128) {
        int r = tid >> 6, b = tid & 63;
        float s = red[r][b] + red[2 + r][b] + red[4 + r][b] + red[6 + r][b];
        dTT[(j0 + r) * 64 + b] = s + b_dec[j0 + r];
    }
}

// ---------------------------------------------------------------------------
// K2 fused: blocks 0..63 -> e/softmax/ctx for batch b=bid.
//           blocks 64..255 -> W_hh gate partials (contiguous row panels).
// ---------------------------------------------------------------------------
__global__ __launch_bounds__(256) void kStep2(
    const float* __restrict__ hT, const float* __restrict__ dTT,
    const float* __restrict__ encat, const float* __restrict__ feat,
    const float* __restrict__ v_w, const float* __restrict__ v_b,
    const float* __restrict__ W_hh, float* __restrict__ ctx,
    float* __restrict__ gH)
{
    const int tid = threadIdx.x, bid = blockIdx.x;
    const int lane = tid & 63, w = tid >> 6;
    if (bid < 64) {
        __shared__ float da[512];
        __shared__ float esh[52];
        __shared__ float al[52];
        const int b = bid;
        da[tid]       = dTT[(size_t)tid * 64 + b];
        da[tid + 256] = dTT[(size_t)(tid + 256) * 64 + b];
        __syncthreads();
        for (int r = w; r < R_; r += 4) {
            const float* er = encat + ((size_t)b * R_ + r) * 512;
            float s = 0.f;
#pragma unroll
            for (int i = 0; i < 8; ++i) {
                int j = i * 64 + lane;
                s += ftanh(er[j] + da[j]) * v_w[j];
            }
#pragma unroll
            for (int off = 32; off; off >>= 1) s += __shfl_down(s, off, 64);
            if (lane == 0) esh[r] = s + v_b[0];
        }
        __syncthreads();
        if (tid < 64) {
            float x = (lane < R_) ? esh[lane] : -1e30f;
            float mx = x;
#pragma unroll
            for (int off = 32; off; off >>= 1) mx = fmaxf(mx, __shfl_xor(mx, off, 64));
            float ex = (lane < R_) ? __expf(x - mx) : 0.f;
            float sm = ex;
#pragma unroll
            for (int off = 32; off; off >>= 1) sm += __shfl_xor(sm, off, 64);
            if (lane < R_) al[lane] = ex / sm;
        }
        __syncthreads();
#pragma unroll
        for (int p = 0; p < 2; ++p) {
            int f = tid + p * 256;
            const float* fp = feat + (size_t)b * R_ * F_ + f;
            float s = 0.f;
            for (int r = 0; r < R_; ++r) s += al[r] * fp[(size_t)r * 512];
            ctx[(size_t)b * 512 + f] = s;
        }
    } else {
        __shared__ float wpan[11 * 512];      // contiguous W_hh row panel
        __shared__ float red2[4][11 * 64];
        const int jb = bid - 64;
        const int n     = (jb < 128) ? 11 : 10;
        const int start = (jb < 128) ? jb * 11 : 1408 + (jb - 128) * 10;
        for (int idx = tid * 4; idx < n * 512; idx += 1024)
            *(float4*)&wpan[idx] = *(const float4*)&W_hh[(size_t)start * 512 + idx];
        __syncthreads();
        float acc[11] = {};
        for (int j4 = 32 * w; j4 < 32 * w + 32; ++j4) {
            int j = j4 * 4;
            float x0 = hT[(j + 0) * 64 + lane];
            float x1 = hT[(j + 1) * 64 + lane];
            float x2 = hT[(j + 2) * 64 + lane];
            float x3 = hT[(j + 3) * 64 + lane];
#pragma unroll
            for (int r = 0; r < 11; ++r) {
                float4 wv = *(const float4*)&wpan[r * 512 + j];
                acc[r] += wv.x * x0 + wv.y * x1 + wv.z * x2 + wv.w * x3;
            }
        }
#pragma unroll
        for (int r = 0; r < 11; ++r) red2[w][r * 64 + lane] = acc[r];
        __syncthreads();
        for (int o = tid; o < n * 64; o += 256) {
            float s = red2[0][o] + red2[1][o] + red2[2][o] + red2[3][o];
            gH[(size_t)(start + (o >> 6)) * 64 + (o & 63)] = s;
        }
    }
}

// ---------------------------------------------------------------------------
// K3: gates = (W_ih[:,512:]*ctx from LDS) + gH + embg; LSTM pointwise.
// Block owns j-pair {2bid, 2bid+1} (8 gate rows). ctx staged as xls[b][524].
// ---------------------------------------------------------------------------
__global__ __launch_bounds__(256) void kStep3(
    const float* __restrict__ ctx, const float* __restrict__ gH,
    const float* __restrict__ embg, const float* __restrict__ W_ih,
    float* __restrict__ cT, float* __restrict__ hTn,
    float* __restrict__ HallT, int t)
{
    __shared__ __align__(16) float xls[64 * 524];   // 134 KB, aligned rows
    __shared__ __align__(16) float wp[8 * 512];     // 16 KB; later: red + gsm
    const int tid = threadIdx.x, bid = blockIdx.x;
    const int lane = tid & 63, w = tid >> 6;
    const int j0 = 2 * bid;

    for (int idx = tid * 4; idx < 64 * 512; idx += 1024) {
        int b = idx >> 9, k = idx & 511;
        *(float4*)&xls[b * 524 + k] = *(const float4*)&ctx[(size_t)b * 512 + k];
    }
    for (int idx = tid * 4; idx < 8 * 512; idx += 1024) {
        int rr = idx >> 9, k = idx & 511;
        int row = (rr >> 1) * 512 + j0 + (rr & 1);
        *(float4*)&wp[idx] = *(const float4*)&W_ih[(size_t)row * 1024 + 512 + k];
    }
    __syncthreads();
    float acc[8] = {};
    const float* xrow = &xls[lane * 524];
    for (int j4 = 32 * w; j4 < 32 * w + 32; ++j4) {
        float4 x = *(const float4*)&xrow[j4 * 4];
#pragma unroll
        for (int r = 0; r < 8; ++r) {
            float4 wv = *(const float4*)&wp[r * 512 + j4 * 4];
            acc[r] += wv.x * x.x + wv.y * x.y + wv.z * x.z + wv.w * x.w;
        }
    }
    __syncthreads();                 // wp reads done
    float* red = wp;                 // [4][512]
#pragma unroll
    for (int r = 0; r < 8; ++r) red[w * 512 + r * 64 + lane] = acc[r];
    __syncthreads();
    float* gsm = wp + 2048;          // [8][64]
    for (int o = tid; o < 512; o += 256) {
        int rr = o >> 6, b = o & 63;
        int row = (rr >> 1) * 512 + j0 + (rr & 1);
        float s = red[o] + red[512 + o] + red[1024 + o] + red[1536 + o]
                + gH[(size_t)row * 64 + b]
                + embg[((size_t)b * TT + t) * 2048 + row];
        gsm[o] = s;
    }
    __syncthreads();
    if (tid < 128) {
        int jr = tid >> 6, b = tid & 63;
        int j = j0 + jr;
        float ig = fsigm(gsm[(0 * 2 + jr) * 64 + b]);
        float fg = fsigm(gsm[(1 * 2 + jr) * 64 + b]);
        float gg = ftanh(gsm[(2 * 2 + jr) * 64 + b]);
        float og = fsigm(gsm[(3 * 2 + jr) * 64 + b]);
        float c  = cT[(size_t)j * 64 + b];
        float cn = fg * c + ig * gg;
        float hn = og * ftanh(cn);
        cT[(size_t)j * 64 + b]  = cn;
        hTn[(size_t)j * 64 + b] = hn;
        HallT[((size_t)t * 512 + j) * 64 + b] = hn;
    }
}

// ---------------------------------------------------------------------------
extern "C" void kernel_launch(void* const* d_in, const int* in_sizes, int n_in,
                              void* d_out, int out_size, void* d_ws, size_t ws_size,
                              hipStream_t stream)
{
    (void)in_sizes; (void)n_in; (void)out_size; (void)ws_size;
    const float* feat     = (const float*)d_in[0];
    const float* caps     = (const float*)d_in[1];
    const float* W_enc    = (const float*)d_in[2];
    const float* b_enc    = (const float*)d_in[3];
    const float* W_dec    = (const float*)d_in[4];
    const float* b_dec    = (const float*)d_in[5];
    const float* v_w      = (const float*)d_in[6];
    const float* v_b      = (const float*)d_in[7];
    const float* W_ih     = (const float*)d_in[8];
    const float* W_hh     = (const float*)d_in[9];
    const float* b_ih     = (const float*)d_in[10];
    const float* b_hh     = (const float*)d_in[11];
    const float* W_init_h = (const float*)d_in[12];
    const float* b_init_h = (const float*)d_in[13];
    const float* W_init_c = (const float*)d_in[14];
    const float* b_init_c = (const float*)d_in[15];
    const float* W_out    = (const float*)d_in[16];
    const float* b_out    = (const float*)d_in[17];
    float* out = (float*)d_out;
    float* ws  = (float*)d_ws;

    // workspace (floats), ~28.4 MB
    float* hT    = ws;                                   // 2 * 32768 ping-pong [j][b]
    float* cT    = ws + 65536;                           // 32768 [j][b]
    float* dTT   = ws + 98304;                           // 32768 [j][b]   (pre: avg)
    float* ctx   = ws + 131072;                          // 32768 [b][k]   (pre: h0tmp)
    float* gH    = ws + 163840;                          // 131072 [row][b](pre: c0tmp)
    float* encat = ws + 294912;                          // 1,605,632
    float* embg  = encat + (size_t)B_ * R_ * H_;         // 4,194,304
    float* HallT = embg + (size_t)B_ * TT * 2048;        // 1,015,808

    float* avg   = dTT;    // dead before kStep1 first writes dTT
    float* h0tmp = ctx;    // dead before kStep2 first writes ctx
    float* c0tmp = gH;     // dead before kStep2 first writes gH
    float* Hall  = embg;   // embg dead after decode loop

    dim3 thr(256);

    k_avg<<<128, thr, 0, stream>>>(feat, avg);
    gemm_nt_f32<<<dim3(8, 1), thr, 0, stream>>>(avg, 512, W_init_h, 512, b_init_h, nullptr,
                                                h0tmp, 512, 64, 512, 512);
    gemm_nt_f32<<<dim3(8, 1), thr, 0, stream>>>(avg, 512, W_init_c, 512, b_init_c, nullptr,
                                                c0tmp, 512, 64, 512, 512);
    gemm_nt_f32<<<dim3(8, 49), thr, 0, stream>>>(feat, 512, W_enc, 512, b_enc, nullptr,
                                                 encat, 512, 3136, 512, 512);
    gemm_nt_f32<<<dim3(32, 32), thr, 0, stream>>>(caps, 512, W_ih, 1024, b_ih, b_hh,
                                                  embg, 2048, 2048, 2048, 512);
    k_tr<<<128, thr, 0, stream>>>(h0tmp, hT);    // h0 -> hT buffer 0
    k_tr<<<128, thr, 0, stream>>>(c0tmp, cT);    // c0 -> cT

    for (int t = 0; t < TS; ++t) {
        const float* hR = hT + (size_t)(t & 1) * (H_ * 64);
        float*       hN = hT + (size_t)((t + 1) & 1) * (H_ * 64);
        kStep1<<<256, thr, 0, stream>>>(hR, W_dec, b_dec, dTT);
        kStep2<<<256, thr, 0, stream>>>(hR, dTT, encat, feat, v_w, v_b, W_hh, ctx, gH);
        kStep3<<<256, thr, 0, stream>>>(ctx, gH, embg, W_ih, cT, hN, HallT, t);
    }

    // HallT[t][j][b] -> Hall[(b*31+t)][j]   (Hall aliases dead embg)
    k_trH<<<3968, thr, 0, stream>>>(HallT, Hall);

    // logits = Hall @ W_out.T + b_out
    gemm_nt_f32<<<dim3(157, 31), thr, 0, stream>>>(Hall, 512, W_out, 512, b_out, nullptr,
                                                   out, 10000, 1984, 10000, 512);
}